// Round 1
// baseline (1758.754 us; speedup 1.0000x reference)
//
#include <hip/hip_runtime.h>

typedef _Float16 f16;
typedef _Float16 f16x8 __attribute__((ext_vector_type(8)));
typedef float floatx4 __attribute__((ext_vector_type(4)));
typedef float floatv4 __attribute__((ext_vector_type(4)));

#define BM 64
#define BN 64
#define BK 64
#define LDSS 72  // LDS row stride in f16 elements: 64 + 8 pad -> 144B rows, uniform banks

__device__ __forceinline__ float ftanh(float x) {
  float ax = __builtin_fabsf(x);
  float e  = __expf(-2.0f * ax);
  float t  = (1.0f - e) * __builtin_amdgcn_rcpf(1.0f + e);
  return x < 0.0f ? -t : t;
}

// C[M,N] = A[M,K] * WT[N,K]^T (+bias) (+U) (tanh) -> f16 out to 1 or 2 destinations.
// Grid: (M/64, N/64), block 256. Kp multiple of 64; A_FP32 path zero-fills k >= Kreal.
template<bool A_FP32, bool HAS_U, bool HAS_BIAS, bool TANH, bool TWO_DEST>
__global__ __launch_bounds__(256)
void gemm_k(const void* __restrict__ Av, int lda, int Kreal, int Kp,
            const f16* __restrict__ WT,
            const f16* __restrict__ U, int ldu,
            const float* __restrict__ bias,
            f16* __restrict__ out1, int ldo1,
            f16* __restrict__ out2, int ldo2)
{
  __shared__ f16 As[BM][LDSS];
  __shared__ f16 Ws[BN][LDSS];
  const int tid  = threadIdx.x;
  const int bm   = blockIdx.x * BM;
  const int bn   = blockIdx.y * BN;
  const int wave = tid >> 6;
  const int lane = tid & 63;
  const int wm   = (wave >> 1) * 32;
  const int wn   = (wave & 1) * 32;
  const int lm   = lane & 15;
  const int quad = lane >> 4;

  const int srow = tid >> 3;       // 0..31 (two passes cover 64 rows)
  const int scol = (tid & 7) * 8;  // 0..56 step 8 (8 f16 = 16B per thread)

  floatx4 zero4 = {0.f, 0.f, 0.f, 0.f};
  floatx4 acc[2][2];
  acc[0][0] = zero4; acc[0][1] = zero4; acc[1][0] = zero4; acc[1][1] = zero4;

  for (int k0 = 0; k0 < Kp; k0 += BK) {
    #pragma unroll
    for (int r = 0; r < 2; ++r) {
      int row = srow + r * 32;
      int gk  = k0 + scol;
      if constexpr (A_FP32) {
        const float* A = (const float*)Av;
        const size_t base = (size_t)(bm + row) * lda;
        union { f16 e[8]; f16x8 v; } t8;
        #pragma unroll
        for (int jj = 0; jj < 8; jj += 4) {
          int kb = gk + jj;
          if (kb + 4 <= Kreal) {
            floatv4 v4 = *(const floatv4*)(A + base + kb);
            t8.e[jj+0] = (f16)v4[0]; t8.e[jj+1] = (f16)v4[1];
            t8.e[jj+2] = (f16)v4[2]; t8.e[jj+3] = (f16)v4[3];
          } else {
            #pragma unroll
            for (int j = 0; j < 4; ++j) {
              int kk2 = kb + j;
              t8.e[jj+j] = (kk2 < Kreal) ? (f16)A[base + kk2] : (f16)0.f;
            }
          }
        }
        *(f16x8*)&As[row][scol] = t8.v;
      } else {
        const f16* A = (const f16*)Av;
        f16x8 v = *(const f16x8*)(A + (size_t)(bm + row) * lda + gk);
        *(f16x8*)&As[row][scol] = v;
      }
      f16x8 w = *(const f16x8*)(WT + (size_t)(bn + row) * Kp + gk);
      *(f16x8*)&Ws[row][scol] = w;
    }
    __syncthreads();
    #pragma unroll
    for (int kk = 0; kk < BK; kk += 32) {
      f16x8 a0 = *(const f16x8*)&As[wm +  0 + lm][kk + quad * 8];
      f16x8 a1 = *(const f16x8*)&As[wm + 16 + lm][kk + quad * 8];
      f16x8 b0 = *(const f16x8*)&Ws[wn +  0 + lm][kk + quad * 8];
      f16x8 b1 = *(const f16x8*)&Ws[wn + 16 + lm][kk + quad * 8];
      acc[0][0] = __builtin_amdgcn_mfma_f32_16x16x32_f16(a0, b0, acc[0][0], 0, 0, 0);
      acc[0][1] = __builtin_amdgcn_mfma_f32_16x16x32_f16(a0, b1, acc[0][1], 0, 0, 0);
      acc[1][0] = __builtin_amdgcn_mfma_f32_16x16x32_f16(a1, b0, acc[1][0], 0, 0, 0);
      acc[1][1] = __builtin_amdgcn_mfma_f32_16x16x32_f16(a1, b1, acc[1][1], 0, 0, 0);
    }
    __syncthreads();
  }

  // Epilogue. C/D layout: col = lane&15, row = quad*4 + reg  [measured m89/m91]
  #pragma unroll
  for (int i = 0; i < 2; ++i) {
    #pragma unroll
    for (int j = 0; j < 2; ++j) {
      int gn = bn + wn + j * 16 + lm;
      float bv = 0.0f;
      if constexpr (HAS_BIAS) bv = bias[gn];
      #pragma unroll
      for (int r = 0; r < 4; ++r) {
        int gm = bm + wm + i * 16 + quad * 4 + r;
        float v = acc[i][j][r] + bv;
        if constexpr (HAS_U) v += (float)U[(size_t)gm * ldu + gn];
        if constexpr (TANH) v = ftanh(v);
        f16 o = (f16)v;
        out1[(size_t)gm * ldo1 + gn] = o;
        if constexpr (TWO_DEST) out2[(size_t)gm * ldo2 + gn] = o;
      }
    }
  }
}

// WceT[n][k] = (W_emb @ wx0)^T, k-contiguous, padded to Kp=320 with zeros.
// bcomb[n] = b0[n] + b_emb @ wx0[:,n]
__global__ void prep_wce(const float* __restrict__ W_emb, const float* __restrict__ wx0,
                         const float* __restrict__ b_emb, const float* __restrict__ b0,
                         f16* __restrict__ WceT, float* __restrict__ bcomb)
{
  int id = blockIdx.x * 256 + threadIdx.x;   // 512*320 = 163840 threads exactly
  int n = id & 511;
  int k = id >> 9;                            // 0..319
  float s = 0.f;
  if (k < 300) {
    for (int j = 0; j < 512; ++j)
      s = __builtin_fmaf(W_emb[k * 512 + j], wx0[j * 512 + n], s);
  }
  WceT[(size_t)n * 320 + k] = (f16)s;
  if (id < 512) {
    float sb = b0[id];
    for (int j = 0; j < 512; ++j)
      sb = __builtin_fmaf(b_emb[j], wx0[j * 512 + id], sb);
    bcomb[id] = sb;
  }
}

// Transposed f16 weights: wh0T[512][512]; W1T/W2T[512][1024] = [wx;wh]^T
__global__ void prep_wt(const float* __restrict__ wh0,
                        const float* __restrict__ wx1, const float* __restrict__ wh1,
                        const float* __restrict__ wx2, const float* __restrict__ wh2,
                        f16* __restrict__ wh0T, f16* __restrict__ W1T, f16* __restrict__ W2T)
{
  int id = blockIdx.x * 256 + threadIdx.x;   // 262144 + 524288 + 524288 = 1310720 exactly
  if (id < 262144) {
    int n = id & 511, k = id >> 9;
    wh0T[(size_t)n * 512 + k] = (f16)wh0[k * 512 + n];
  } else if (id < 262144 + 524288) {
    int id2 = id - 262144;
    int n = id2 & 511, k = id2 >> 9;         // 0..1023
    float v = (k < 512) ? wx1[k * 512 + n] : wh1[(k - 512) * 512 + n];
    W1T[(size_t)n * 1024 + k] = (f16)v;
  } else {
    int id2 = id - 262144 - 524288;
    int n = id2 & 511, k = id2 >> 9;
    float v = (k < 512) ? wx2[k * 512 + n] : wh2[(k - 512) * 512 + n];
    W2T[(size_t)n * 1024 + k] = (f16)v;
  }
}

// out[4096,10] = h2[4096,512](f16, lda) @ W_fc[512,10] + b_fc
__global__ void fc_kernel(const f16* __restrict__ h2, int lda,
                          const float* __restrict__ Wfc, const float* __restrict__ bfc,
                          float* __restrict__ out)
{
  int id = blockIdx.x * 256 + threadIdx.x;   // 160*256 = 40960 exactly
  int row = id / 10;
  int c = id - row * 10;
  float s = bfc[c];
  const f16* hr = h2 + (size_t)row * lda;
  #pragma unroll 8
  for (int k = 0; k < 512; ++k)
    s = __builtin_fmaf((float)hr[k], Wfc[k * 10 + c], s);
  out[id] = s;
}

extern "C" void kernel_launch(void* const* d_in, const int* in_sizes, int n_in,
                              void* d_out, int out_size, void* d_ws, size_t ws_size,
                              hipStream_t stream)
{
  (void)in_sizes; (void)n_in; (void)out_size; (void)ws_size;
  const float* x     = (const float*)d_in[0];
  const float* W_emb = (const float*)d_in[1];
  const float* b_emb = (const float*)d_in[2];
  const float* wx0   = (const float*)d_in[3];
  const float* wh0   = (const float*)d_in[4];
  const float* b0    = (const float*)d_in[5];
  const float* wx1   = (const float*)d_in[6];
  const float* wh1   = (const float*)d_in[7];
  const float* b1    = (const float*)d_in[8];
  const float* wx2   = (const float*)d_in[9];
  const float* wh2   = (const float*)d_in[10];
  const float* b2    = (const float*)d_in[11];
  const float* W_fc  = (const float*)d_in[12];
  const float* b_fc  = (const float*)d_in[13];
  float* out = (float*)d_out;

  char* ws = (char*)d_ws;
  size_t off = 0;
  auto alloc = [&](size_t bytes) -> void* {
    void* p = ws + off;
    off = (off + bytes + 255) & ~(size_t)255;
    return p;
  };
  f16*   WceT  = (f16*)alloc((size_t)512 * 320 * 2);
  f16*   wh0T  = (f16*)alloc((size_t)512 * 512 * 2);
  f16*   W1T   = (f16*)alloc((size_t)512 * 1024 * 2);
  f16*   W2T   = (f16*)alloc((size_t)512 * 1024 * 2);
  float* bcomb = (float*)alloc(512 * 4);
  f16*   u0    = (f16*)alloc((size_t)81920 * 512 * 2);
  f16*   A0[2], *A1[2], *A2[2];
  A0[0] = (f16*)alloc((size_t)4096 * 512 * 2);
  A0[1] = (f16*)alloc((size_t)4096 * 512 * 2);
  A1[0] = (f16*)alloc((size_t)4096 * 1024 * 2);
  A1[1] = (f16*)alloc((size_t)4096 * 1024 * 2);
  A2[0] = (f16*)alloc((size_t)4096 * 1024 * 2);
  A2[1] = (f16*)alloc((size_t)4096 * 1024 * 2);

  // weight prep (once per call; inputs are restored each call)
  prep_wce<<<640, 256, 0, stream>>>(W_emb, wx0, b_emb, b0, WceT, bcomb);
  prep_wt<<<5120, 256, 0, stream>>>(wh0, wx1, wh1, wx2, wh2, wh0T, W1T, W2T);

  // zero initial hidden states (ws is poisoned 0xAA each call)
  hipMemsetAsync(A0[0], 0, (size_t)4096 * 512 * 2, stream);
  hipMemsetAsync(A1[0], 0, (size_t)4096 * 1024 * 2, stream);
  hipMemsetAsync(A2[0], 0, (size_t)4096 * 1024 * 2, stream);

  // u0[b*20+t][n] = x @ (W_emb*wx0) + bcomb   (all timesteps, one parallel GEMM)
  gemm_k<true, false, true, false, false><<<dim3(1280, 8), 256, 0, stream>>>(
      (const void*)x, 300, 300, 320, WceT, nullptr, 0, bcomb, u0, 512, nullptr, 0);

  for (int t = 0; t < 20; ++t) {
    int cur = t & 1, nxt = (t + 1) & 1;
    // layer 0: h0 = tanh(u0_t + h0_prev @ wh0); write to A0[nxt] and A1[cur][:, :512]
    gemm_k<false, true, false, true, true><<<dim3(64, 8), 256, 0, stream>>>(
        (const void*)A0[cur], 512, 512, 512, wh0T, u0 + (size_t)t * 512, 10240,
        nullptr, A0[nxt], 512, A1[cur], 1024);
    // layer 1: h1 = tanh([h0_t, h1_prev] @ [wx1;wh1] + b1); -> A2[cur][:, :512], A1[nxt][:, 512:]
    gemm_k<false, false, true, true, true><<<dim3(64, 8), 256, 0, stream>>>(
        (const void*)A1[cur], 1024, 1024, 1024, W1T, nullptr, 0, b1,
        A2[cur], 1024, A1[nxt] + 512, 1024);
    // layer 2: h2 = tanh([h1_t, h2_prev] @ [wx2;wh2] + b2); -> A2[nxt][:, 512:]
    gemm_k<false, false, true, true, false><<<dim3(64, 8), 256, 0, stream>>>(
        (const void*)A2[cur], 1024, 1024, 1024, W2T, nullptr, 0, b2,
        A2[nxt] + 512, 1024, nullptr, 0);
  }

  // final h2 lives in A2[(19+1)&1 = 0][:, 512:]
  fc_kernel<<<160, 256, 0, stream>>>(A2[0] + 512, 1024, W_fc, b_fc, out);
}

// Round 2
// 1163.908 us; speedup vs baseline: 1.5111x; 1.5111x over previous
//
#include <hip/hip_runtime.h>

typedef _Float16 f16;
typedef _Float16 f16x8 __attribute__((ext_vector_type(8)));
typedef float floatx4 __attribute__((ext_vector_type(4)));
typedef float floatv4 __attribute__((ext_vector_type(4)));

#define BM 64
#define BN 64
#define BK 64
#define LDSS 72  // LDS row stride in f16: 64 + 8 pad -> 144B rows

struct SubGemm {
  const void* A;      // f16 (or fp32 when A_FP32 template path)
  const f16* WT;      // [512][K] k-contiguous
  const f16* U;       // optional additive pre-activation term
  const float* bias;  // optional
  f16* out1;
  f16* out2;          // optional second destination
  int K;              // padded K: loop bound AND WT row stride (multiple of 64)
  int lda;            // A row stride in elements
  int Kreal;          // valid K (fp32 path zero-fills beyond)
  int ldu, ldo1, ldo2;
  int dotanh;
};

__device__ __forceinline__ float ftanh(float x) {
  float ax = __builtin_fabsf(x);
  float e  = __expf(-2.0f * ax);
  float t  = (1.0f - e) * __builtin_amdgcn_rcpf(1.0f + e);
  return x < 0.0f ? -t : t;
}

// Generic 64x64-tile MFMA GEMM. Grid: (N/64 fastest for A-tile L2 reuse, M/64, nsub).
// blockIdx.z selects one of up to 3 independent sub-GEMMs (wavefront batching).
template<bool A_FP32>
__global__ __launch_bounds__(256)
void gemm_wave(SubGemm g0, SubGemm g1, SubGemm g2)
{
  SubGemm g = g0;
  if (blockIdx.z == 1) g = g1;
  else if (blockIdx.z == 2) g = g2;

  __shared__ f16 As[BM][LDSS];
  __shared__ f16 Ws[BN][LDSS];
  const int tid  = threadIdx.x;
  const int bn   = blockIdx.x * BN;   // N fastest
  const int bm   = blockIdx.y * BM;
  const int wave = tid >> 6;
  const int lane = tid & 63;
  const int wm   = (wave >> 1) * 32;
  const int wn   = (wave & 1) * 32;
  const int lm   = lane & 15;
  const int quad = lane >> 4;

  const int srow = tid >> 3;       // 0..31 (two passes cover 64 rows)
  const int scol = (tid & 7) * 8;  // 0..56 step 8 (16B per thread)

  floatx4 zero4 = {0.f, 0.f, 0.f, 0.f};
  floatx4 acc[2][2];
  acc[0][0] = zero4; acc[0][1] = zero4; acc[1][0] = zero4; acc[1][1] = zero4;

  for (int k0 = 0; k0 < g.K; k0 += BK) {
    #pragma unroll
    for (int r = 0; r < 2; ++r) {
      int row = srow + r * 32;
      int gk  = k0 + scol;
      if constexpr (A_FP32) {
        const float* A = (const float*)g.A;
        const size_t base = (size_t)(bm + row) * g.lda;
        union { f16 e[8]; f16x8 v; } t8;
        #pragma unroll
        for (int jj = 0; jj < 8; jj += 4) {
          int kb = gk + jj;
          if (kb + 4 <= g.Kreal) {
            floatv4 v4 = *(const floatv4*)(A + base + kb);
            t8.e[jj+0] = (f16)v4[0]; t8.e[jj+1] = (f16)v4[1];
            t8.e[jj+2] = (f16)v4[2]; t8.e[jj+3] = (f16)v4[3];
          } else {
            #pragma unroll
            for (int j = 0; j < 4; ++j) {
              int kk2 = kb + j;
              t8.e[jj+j] = (kk2 < g.Kreal) ? (f16)A[base + kk2] : (f16)0.f;
            }
          }
        }
        *(f16x8*)&As[row][scol] = t8.v;
      } else {
        const f16* A = (const f16*)g.A;
        *(f16x8*)&As[row][scol] = *(const f16x8*)(A + (size_t)(bm + row) * g.lda + gk);
      }
      *(f16x8*)&Ws[row][scol] = *(const f16x8*)(g.WT + (size_t)(bn + row) * g.K + gk);
    }
    __syncthreads();
    #pragma unroll
    for (int kk = 0; kk < BK; kk += 32) {
      f16x8 a0 = *(const f16x8*)&As[wm +  0 + lm][kk + quad * 8];
      f16x8 a1 = *(const f16x8*)&As[wm + 16 + lm][kk + quad * 8];
      f16x8 b0 = *(const f16x8*)&Ws[wn +  0 + lm][kk + quad * 8];
      f16x8 b1 = *(const f16x8*)&Ws[wn + 16 + lm][kk + quad * 8];
      acc[0][0] = __builtin_amdgcn_mfma_f32_16x16x32_f16(a0, b0, acc[0][0], 0, 0, 0);
      acc[0][1] = __builtin_amdgcn_mfma_f32_16x16x32_f16(a0, b1, acc[0][1], 0, 0, 0);
      acc[1][0] = __builtin_amdgcn_mfma_f32_16x16x32_f16(a1, b0, acc[1][0], 0, 0, 0);
      acc[1][1] = __builtin_amdgcn_mfma_f32_16x16x32_f16(a1, b1, acc[1][1], 0, 0, 0);
    }
    __syncthreads();
  }

  // C/D layout: col = lane&15, row = quad*4 + reg  [measured m89/m91]
  #pragma unroll
  for (int i = 0; i < 2; ++i) {
    #pragma unroll
    for (int j = 0; j < 2; ++j) {
      int gn = bn + wn + j * 16 + lm;
      float bv = g.bias ? g.bias[gn] : 0.f;
      #pragma unroll
      for (int r = 0; r < 4; ++r) {
        int gm = bm + wm + i * 16 + quad * 4 + r;
        float v = acc[i][j][r] + bv;
        if (g.U) v += (float)g.U[(size_t)gm * g.ldu + gn];
        if (g.dotanh) v = ftanh(v);
        f16 o = (f16)v;
        g.out1[(size_t)gm * g.ldo1 + gn] = o;
        if (g.out2) g.out2[(size_t)gm * g.ldo2 + gn] = o;
      }
    }
  }
}

// WceT[n][k] = (W_emb @ wx0)^T, k-contiguous, padded to Kp=320 with zeros.
// bcomb[n] = b0[n] + b_emb @ wx0[:,n]
__global__ void prep_wce(const float* __restrict__ W_emb, const float* __restrict__ wx0,
                         const float* __restrict__ b_emb, const float* __restrict__ b0,
                         f16* __restrict__ WceT, float* __restrict__ bcomb)
{
  int id = blockIdx.x * 256 + threadIdx.x;   // 512*320 = 163840 threads exactly
  int n = id & 511;
  int k = id >> 9;                            // 0..319
  float s = 0.f;
  if (k < 300) {
    for (int j = 0; j < 512; ++j)
      s = __builtin_fmaf(W_emb[k * 512 + j], wx0[j * 512 + n], s);
  }
  WceT[(size_t)n * 320 + k] = (f16)s;
  if (id < 512) {
    float sb = b0[id];
    for (int j = 0; j < 512; ++j)
      sb = __builtin_fmaf(b_emb[j], wx0[j * 512 + id], sb);
    bcomb[id] = sb;
  }
}

// Transposed f16 weights: wh0T[512][512]; W1T/W2T[512][1024] = [wx;wh]^T
__global__ void prep_wt(const float* __restrict__ wh0,
                        const float* __restrict__ wx1, const float* __restrict__ wh1,
                        const float* __restrict__ wx2, const float* __restrict__ wh2,
                        f16* __restrict__ wh0T, f16* __restrict__ W1T, f16* __restrict__ W2T)
{
  int id = blockIdx.x * 256 + threadIdx.x;   // 1310720 exactly
  if (id < 262144) {
    int n = id & 511, k = id >> 9;
    wh0T[(size_t)n * 512 + k] = (f16)wh0[k * 512 + n];
  } else if (id < 262144 + 524288) {
    int id2 = id - 262144;
    int n = id2 & 511, k = id2 >> 9;         // 0..1023
    float v = (k < 512) ? wx1[k * 512 + n] : wh1[(k - 512) * 512 + n];
    W1T[(size_t)n * 1024 + k] = (f16)v;
  } else {
    int id2 = id - 262144 - 524288;
    int n = id2 & 511, k = id2 >> 9;
    float v = (k < 512) ? wx2[k * 512 + n] : wh2[(k - 512) * 512 + n];
    W2T[(size_t)n * 1024 + k] = (f16)v;
  }
}

// out[4096,10] = h2[4096,512](f16, lda) @ W_fc[512,10] + b_fc
__global__ void fc_kernel(const f16* __restrict__ h2, int lda,
                          const float* __restrict__ Wfc, const float* __restrict__ bfc,
                          float* __restrict__ out)
{
  int id = blockIdx.x * 256 + threadIdx.x;   // 160*256 = 40960 exactly
  int row = id / 10;
  int c = id - row * 10;
  float s = bfc[c];
  const f16* hr = h2 + (size_t)row * lda;
  #pragma unroll 8
  for (int k = 0; k < 512; ++k)
    s = __builtin_fmaf((float)hr[k], Wfc[k * 10 + c], s);
  out[id] = s;
}

extern "C" void kernel_launch(void* const* d_in, const int* in_sizes, int n_in,
                              void* d_out, int out_size, void* d_ws, size_t ws_size,
                              hipStream_t stream)
{
  (void)in_sizes; (void)n_in; (void)out_size; (void)ws_size;
  const float* x     = (const float*)d_in[0];
  const float* W_emb = (const float*)d_in[1];
  const float* b_emb = (const float*)d_in[2];
  const float* wx0   = (const float*)d_in[3];
  const float* wh0   = (const float*)d_in[4];
  const float* b0    = (const float*)d_in[5];
  const float* wx1   = (const float*)d_in[6];
  const float* wh1   = (const float*)d_in[7];
  const float* b1    = (const float*)d_in[8];
  const float* wx2   = (const float*)d_in[9];
  const float* wh2   = (const float*)d_in[10];
  const float* b2    = (const float*)d_in[11];
  const float* W_fc  = (const float*)d_in[12];
  const float* b_fc  = (const float*)d_in[13];
  float* out = (float*)d_out;

  char* ws = (char*)d_ws;
  size_t off = 0;
  auto alloc = [&](size_t bytes) -> void* {
    void* p = ws + off;
    off = (off + bytes + 255) & ~(size_t)255;
    return p;
  };
  f16*   WceT  = (f16*)alloc((size_t)512 * 320 * 2);
  f16*   wh0T  = (f16*)alloc((size_t)512 * 512 * 2);
  f16*   W1T   = (f16*)alloc((size_t)512 * 1024 * 2);
  f16*   W2T   = (f16*)alloc((size_t)512 * 1024 * 2);
  float* bcomb = (float*)alloc(512 * 4);
  f16*   u0    = (f16*)alloc((size_t)81920 * 512 * 2);
  f16*   A0[2], *A1[2], *A2[2];
  A0[0] = (f16*)alloc((size_t)4096 * 512 * 2);
  A0[1] = (f16*)alloc((size_t)4096 * 512 * 2);
  A1[0] = (f16*)alloc((size_t)4096 * 1024 * 2);
  A1[1] = (f16*)alloc((size_t)4096 * 1024 * 2);
  A2[0] = (f16*)alloc((size_t)4096 * 1024 * 2);
  A2[1] = (f16*)alloc((size_t)4096 * 1024 * 2);

  prep_wce<<<640, 256, 0, stream>>>(W_emb, wx0, b_emb, b0, WceT, bcomb);
  prep_wt<<<5120, 256, 0, stream>>>(wh0, wx1, wh1, wx2, wh2, wh0T, W1T, W2T);

  // zero-init: h0(-1)=0; A1[1] (read at w=1) h1(-1)=0 half; A2[0] (read at w=2) h2(-1)=0 half.
  hipMemsetAsync(A0[0], 0, (size_t)4096 * 512 * 2, stream);
  hipMemsetAsync(A1[1], 0, (size_t)4096 * 1024 * 2, stream);
  hipMemsetAsync(A2[0], 0, (size_t)4096 * 1024 * 2, stream);

  auto mk = [](const void* A, const f16* WT, const f16* U, const float* bias,
               f16* o1, f16* o2, int K, int lda, int Kreal,
               int ldu, int ldo1, int ldo2, int th) {
    SubGemm s;
    s.A = A; s.WT = WT; s.U = U; s.bias = bias; s.out1 = o1; s.out2 = o2;
    s.K = K; s.lda = lda; s.Kreal = Kreal;
    s.ldu = ldu; s.ldo1 = ldo1; s.ldo2 = ldo2; s.dotanh = th;
    return s;
  };

  // u0[b*20+t][n] = x @ (W_emb*wx0) + bcomb  — one parallel GEMM, N-fastest grid.
  SubGemm gu = mk(x, WceT, nullptr, bcomb, u0, nullptr, 320, 300, 300, 0, 512, 0, 0);
  gemm_wave<true><<<dim3(8, 1280, 1), 256, 0, stream>>>(gu, gu, gu);

  // Anti-diagonal wavefronts: at wavefront w compute L0(t=w), L1(t=w-1), L2(t=w-2).
  // All reads from [cur], all writes to [nxt]; intra-launch buffers are disjoint.
  for (int w = 0; w <= 21; ++w) {
    int cur = w & 1, nxt = cur ^ 1;
    SubGemm gs[3]; int ng = 0;
    if (w <= 19) {  // L0: h0 = tanh(h0_prev @ wh0 + u0_t) -> A0[nxt], A1[nxt][:, :512]
      gs[ng++] = mk(A0[cur], wh0T, u0 + (size_t)w * 512, nullptr,
                    A0[nxt], A1[nxt], 512, 512, 512, 10240, 512, 1024, 1);
    }
    if (w >= 1 && w <= 20) {  // L1: h1 = tanh([h0_t,h1_prev]@[wx1;wh1]+b1) -> A2[nxt][:, :512], A1[nxt][:,512:]
      gs[ng++] = mk(A1[cur], W1T, nullptr, b1,
                    A2[nxt], A1[nxt] + 512, 1024, 1024, 1024, 0, 1024, 1024, 1);
    }
    if (w >= 2) {   // L2: h2 = tanh([h1_t,h2_prev]@[wx2;wh2]+b2) -> A2[nxt][:,512:]
      gs[ng++] = mk(A2[cur], W2T, nullptr, b2,
                    A2[nxt] + 512, nullptr, 1024, 1024, 1024, 0, 1024, 0, 1);
    }
    gemm_wave<false><<<dim3(8, 64, ng), 256, 0, stream>>>(
        gs[0], gs[ng > 1 ? 1 : 0], gs[ng > 2 ? 2 : 0]);
  }

  // h2(19) ended in A2[(21+1)&1 = 0][:, 512:]
  fc_kernel<<<160, 256, 0, stream>>>(A2[0] + 512, 1024, W_fc, b_fc, out);
}

// Round 3
// 906.542 us; speedup vs baseline: 1.9401x; 1.2839x over previous
//
#include <hip/hip_runtime.h>

typedef _Float16 f16;
typedef _Float16 f16x8 __attribute__((ext_vector_type(8)));
typedef float floatx4 __attribute__((ext_vector_type(4)));

struct SubGemm {
  const void* A;      // f16 (or fp32 when A_FP32 path)
  const f16* WT;      // [N][K] k-contiguous, row stride = K
  const f16* U;       // optional additive pre-activation term
  const float* bias;  // optional
  f16* out1;
  f16* out2;          // optional second destination
  int K;              // padded K (mult of 64): loop bound AND WT row stride
  int lda;            // A row stride in elements
  int Kreal;          // valid K (fp32 path zero-fills beyond)
  int ldu, ldo1, ldo2;
  int dotanh;
};

__device__ __forceinline__ float ftanh(float x) {
  float ax = __builtin_fabsf(x);
  float e  = __expf(-2.0f * ax);
  float t  = (1.0f - e) * __builtin_amdgcn_rcpf(1.0f + e);
  return x < 0.0f ? -t : t;
}

// async global->LDS, 16B per lane. LDS dest must be wave-uniform; HW scatters
// lane i to ldsbase + i*16 [m97/m104]. So LDS layout is row-major UNPADDED.
__device__ __forceinline__ void gll16(const f16* g, f16* l) {
  __builtin_amdgcn_global_load_lds(
      (const __attribute__((address_space(1))) void*)g,
      (__attribute__((address_space(3))) void*)l, 16, 0, 0);
}

// m97-structure GEMM: 128 x (FJ*32) tile, BK=64, 4 waves (2x2), wave tile 64 x FJ*16,
// 4xFJ frags of mfma_f32_16x16x32_f16. XCD-swizzled block mapping:
// id = by*gridDim.x+bx; xcd = id&7; per-XCD M-slab, N fastest within slab.
template<int FJ, bool A_FP32>
__global__ __launch_bounds__(256)
void gemm97(SubGemm g0, SubGemm g1, SubGemm g2, int NB, int nbshift, int mslab)
{
  constexpr int TM = 128;
  constexpr int TN = FJ * 32;
  SubGemm g = g0;
  if (blockIdx.z == 1) g = g1;
  else if (blockIdx.z == 2) g = g2;

  __shared__ f16 sm[TM * 64 + TN * 64];
  f16* As0 = sm;
  f16* Ws0 = sm + TM * 64;

  const int tid  = threadIdx.x;
  const int w    = tid >> 6;
  const int lane = tid & 63;
  const int lm   = lane & 15;
  const int quad = lane >> 4;
  const int wm   = (w >> 1) * 64;
  const int wn   = (w & 1) * (FJ * 16);

  const int id  = blockIdx.y * gridDim.x + blockIdx.x;  // hw-linear within z-slice
  const int xcd = id & 7;
  const int s   = id >> 3;
  const int bm  = (xcd * mslab + (s >> nbshift)) * TM;
  const int bn  = (s & (NB - 1)) * TN;

  const int srow8 = lane >> 3;        // 0..7
  const int scol  = (lane & 7) * 8;   // 0..56 halves (16B)

  floatx4 acc[4][FJ];
  #pragma unroll
  for (int i = 0; i < 4; ++i)
    #pragma unroll
    for (int j = 0; j < FJ; ++j)
      acc[i][j] = (floatx4){0.f, 0.f, 0.f, 0.f};

  constexpr int WC = TN / 32;   // W staging calls per wave

  for (int k0 = 0; k0 < g.K; k0 += 64) {
    if constexpr (A_FP32) {
      const float* Af = (const float*)g.A;
      #pragma unroll
      for (int i = 0; i < 4; ++i) {
        int r  = (w * 4 + i) * 8 + srow8;
        int gk = k0 + scol;
        const float* src = Af + (size_t)(bm + r) * g.lda + gk;
        union { f16 e[8]; f16x8 v; } t;
        if (gk + 8 <= g.Kreal) {
          floatx4 v0 = *(const floatx4*)src;
          floatx4 v1 = *(const floatx4*)(src + 4);
          t.e[0] = (f16)v0[0]; t.e[1] = (f16)v0[1]; t.e[2] = (f16)v0[2]; t.e[3] = (f16)v0[3];
          t.e[4] = (f16)v1[0]; t.e[5] = (f16)v1[1]; t.e[6] = (f16)v1[2]; t.e[7] = (f16)v1[3];
        } else {
          #pragma unroll
          for (int j = 0; j < 8; ++j)
            t.e[j] = (gk + j < g.Kreal) ? (f16)src[j] : (f16)0.f;
        }
        *(f16x8*)&As0[(size_t)(w * 4 + i) * 512 + lane * 8] = t.v;
      }
    } else {
      const f16* Ah = (const f16*)g.A;
      #pragma unroll
      for (int i = 0; i < 4; ++i) {
        int r = (w * 4 + i) * 8 + srow8;
        gll16(Ah + (size_t)(bm + r) * g.lda + k0 + scol, As0 + (w * 4 + i) * 512);
      }
    }
    #pragma unroll
    for (int i = 0; i < WC; ++i) {
      int r = (w * WC + i) * 8 + srow8;
      gll16(g.WT + (size_t)(bn + r) * g.K + k0 + scol, Ws0 + (w * WC + i) * 512);
    }
    __syncthreads();
    #pragma unroll
    for (int kk = 0; kk < 64; kk += 32) {
      f16x8 a[4], b[FJ];
      #pragma unroll
      for (int fi = 0; fi < 4; ++fi)
        a[fi] = *(const f16x8*)&As0[(size_t)(wm + fi * 16 + lm) * 64 + kk + quad * 8];
      #pragma unroll
      for (int fj = 0; fj < FJ; ++fj)
        b[fj] = *(const f16x8*)&Ws0[(size_t)(wn + fj * 16 + lm) * 64 + kk + quad * 8];
      #pragma unroll
      for (int fi = 0; fi < 4; ++fi)
        #pragma unroll
        for (int fj = 0; fj < FJ; ++fj)
          acc[fi][fj] = __builtin_amdgcn_mfma_f32_16x16x32_f16(a[fi], b[fj], acc[fi][fj], 0, 0, 0);
    }
    __syncthreads();
  }

  // C/D layout: col = lane&15, row = quad*4 + reg  [m89/m91]
  #pragma unroll
  for (int fi = 0; fi < 4; ++fi) {
    #pragma unroll
    for (int fj = 0; fj < FJ; ++fj) {
      int gn = bn + wn + fj * 16 + lm;
      float bv = g.bias ? g.bias[gn] : 0.f;
      #pragma unroll
      for (int r = 0; r < 4; ++r) {
        int gm = bm + wm + fi * 16 + quad * 4 + r;
        float v = acc[fi][fj][r] + bv;
        if (g.U) v += (float)g.U[(size_t)gm * g.ldu + gn];
        if (g.dotanh) v = ftanh(v);
        f16 o = (f16)v;
        g.out1[(size_t)gm * g.ldo1 + gn] = o;
        if (g.out2) g.out2[(size_t)gm * g.ldo2 + gn] = o;
      }
    }
  }
}

// WceT[n][k] = (W_emb @ wx0)^T, k-contiguous, padded to Kp=320 with zeros.
// bcomb[n] = b0[n] + b_emb @ wx0[:,n]
__global__ void prep_wce(const float* __restrict__ W_emb, const float* __restrict__ wx0,
                         const float* __restrict__ b_emb, const float* __restrict__ b0,
                         f16* __restrict__ WceT, float* __restrict__ bcomb)
{
  int id = blockIdx.x * 256 + threadIdx.x;   // 512*320 = 163840 threads exactly
  int n = id & 511;
  int k = id >> 9;                            // 0..319
  float s = 0.f;
  if (k < 300) {
    for (int j = 0; j < 512; ++j)
      s = __builtin_fmaf(W_emb[k * 512 + j], wx0[j * 512 + n], s);
  }
  WceT[(size_t)n * 320 + k] = (f16)s;
  if (id < 512) {
    float sb = b0[id];
    for (int j = 0; j < 512; ++j)
      sb = __builtin_fmaf(b_emb[j], wx0[j * 512 + id], sb);
    bcomb[id] = sb;
  }
}

// Transposed f16 weights: wh0T[512][512]; W1T/W2T[512][1024] = [wx;wh]^T
__global__ void prep_wt(const float* __restrict__ wh0,
                        const float* __restrict__ wx1, const float* __restrict__ wh1,
                        const float* __restrict__ wx2, const float* __restrict__ wh2,
                        f16* __restrict__ wh0T, f16* __restrict__ W1T, f16* __restrict__ W2T)
{
  int id = blockIdx.x * 256 + threadIdx.x;   // 1310720 exactly
  if (id < 262144) {
    int n = id & 511, k = id >> 9;
    wh0T[(size_t)n * 512 + k] = (f16)wh0[k * 512 + n];
  } else if (id < 262144 + 524288) {
    int id2 = id - 262144;
    int n = id2 & 511, k = id2 >> 9;         // 0..1023
    float v = (k < 512) ? wx1[k * 512 + n] : wh1[(k - 512) * 512 + n];
    W1T[(size_t)n * 1024 + k] = (f16)v;
  } else {
    int id2 = id - 262144 - 524288;
    int n = id2 & 511, k = id2 >> 9;
    float v = (k < 512) ? wx2[k * 512 + n] : wh2[(k - 512) * 512 + n];
    W2T[(size_t)n * 1024 + k] = (f16)v;
  }
}

// out[4096,10] = h2[4096,512](f16, lda) @ W_fc[512,10] + b_fc
__global__ void fc_kernel(const f16* __restrict__ h2, int lda,
                          const float* __restrict__ Wfc, const float* __restrict__ bfc,
                          float* __restrict__ out)
{
  int id = blockIdx.x * 256 + threadIdx.x;   // 160*256 = 40960 exactly
  int row = id / 10;
  int c = id - row * 10;
  float s = bfc[c];
  const f16* hr = h2 + (size_t)row * lda;
  #pragma unroll 8
  for (int k = 0; k < 512; ++k)
    s = __builtin_fmaf((float)hr[k], Wfc[k * 10 + c], s);
  out[id] = s;
}

extern "C" void kernel_launch(void* const* d_in, const int* in_sizes, int n_in,
                              void* d_out, int out_size, void* d_ws, size_t ws_size,
                              hipStream_t stream)
{
  (void)in_sizes; (void)n_in; (void)out_size; (void)ws_size;
  const float* x     = (const float*)d_in[0];
  const float* W_emb = (const float*)d_in[1];
  const float* b_emb = (const float*)d_in[2];
  const float* wx0   = (const float*)d_in[3];
  const float* wh0   = (const float*)d_in[4];
  const float* b0    = (const float*)d_in[5];
  const float* wx1   = (const float*)d_in[6];
  const float* wh1   = (const float*)d_in[7];
  const float* b1    = (const float*)d_in[8];
  const float* wx2   = (const float*)d_in[9];
  const float* wh2   = (const float*)d_in[10];
  const float* b2    = (const float*)d_in[11];
  const float* W_fc  = (const float*)d_in[12];
  const float* b_fc  = (const float*)d_in[13];
  float* out = (float*)d_out;

  char* ws = (char*)d_ws;
  size_t off = 0;
  auto alloc = [&](size_t bytes) -> void* {
    void* p = ws + off;
    off = (off + bytes + 255) & ~(size_t)255;
    return p;
  };
  f16*   WceT  = (f16*)alloc((size_t)512 * 320 * 2);
  f16*   wh0T  = (f16*)alloc((size_t)512 * 512 * 2);
  f16*   W1T   = (f16*)alloc((size_t)512 * 1024 * 2);
  f16*   W2T   = (f16*)alloc((size_t)512 * 1024 * 2);
  float* bcomb = (float*)alloc(512 * 4);
  f16*   u0    = (f16*)alloc((size_t)81920 * 512 * 2);
  f16*   A0[2], *A1[2], *A2[2];
  A0[0] = (f16*)alloc((size_t)4096 * 512 * 2);
  A0[1] = (f16*)alloc((size_t)4096 * 512 * 2);
  A1[0] = (f16*)alloc((size_t)4096 * 1024 * 2);
  A1[1] = (f16*)alloc((size_t)4096 * 1024 * 2);
  A2[0] = (f16*)alloc((size_t)4096 * 1024 * 2);
  A2[1] = (f16*)alloc((size_t)4096 * 1024 * 2);

  prep_wce<<<640, 256, 0, stream>>>(W_emb, wx0, b_emb, b0, WceT, bcomb);
  prep_wt<<<5120, 256, 0, stream>>>(wh0, wx1, wh1, wx2, wh2, wh0T, W1T, W2T);

  // zero-init: h0(-1) in A0[0]; h1(-1) in A1[1][:,512:]; h2(-1) in A2[0][:,512:].
  hipMemsetAsync(A0[0], 0, (size_t)4096 * 512 * 2, stream);
  hipMemsetAsync(A1[1], 0, (size_t)4096 * 1024 * 2, stream);
  hipMemsetAsync(A2[0], 0, (size_t)4096 * 1024 * 2, stream);

  auto mk = [](const void* A, const f16* WT, const f16* U, const float* bias,
               f16* o1, f16* o2, int K, int lda, int Kreal,
               int ldu, int ldo1, int ldo2, int th) {
    SubGemm s;
    s.A = A; s.WT = WT; s.U = U; s.bias = bias; s.out1 = o1; s.out2 = o2;
    s.K = K; s.lda = lda; s.Kreal = Kreal;
    s.ldu = ldu; s.ldo1 = ldo1; s.ldo2 = ldo2; s.dotanh = th;
    return s;
  };

  // u0 = x @ (W_emb*wx0) + bcomb : M=81920 (MB=640), N=512 (NB=4, TN=128), K=320.
  SubGemm gu = mk(x, WceT, nullptr, bcomb, u0, nullptr, 320, 300, 300, 0, 512, 0, 0);
  gemm97<4, true><<<dim3(4, 640, 1), 256, 0, stream>>>(gu, gu, gu, 4, 2, 80);

  // Anti-diagonal wavefronts: L0(t=w), L1(t=w-1), L2(t=w-2). Tiles 128x64:
  // MB=32, NB=8 -> 256 blocks/sub, x3 subs = 768 blocks (3/CU).
  for (int w = 0; w <= 21; ++w) {
    int cur = w & 1, nxt = cur ^ 1;
    SubGemm gs[3]; int ng = 0;
    if (w <= 19) {  // L0: h0 = tanh(h0_prev @ wh0 + u0_t) -> A0[nxt], A1[nxt][:, :512]
      gs[ng++] = mk(A0[cur], wh0T, u0 + (size_t)w * 512, nullptr,
                    A0[nxt], A1[nxt], 512, 512, 512, 10240, 512, 1024, 1);
    }
    if (w >= 1 && w <= 20) {  // L1 -> A2[nxt][:, :512], A1[nxt][:, 512:]
      gs[ng++] = mk(A1[cur], W1T, nullptr, b1,
                    A2[nxt], A1[nxt] + 512, 1024, 1024, 1024, 0, 1024, 1024, 1);
    }
    if (w >= 2) {   // L2 -> A2[nxt][:, 512:]
      gs[ng++] = mk(A2[cur], W2T, nullptr, b2,
                    A2[nxt] + 512, nullptr, 1024, 1024, 1024, 0, 1024, 0, 1);
    }
    gemm97<2, false><<<dim3(8, 32, ng), 256, 0, stream>>>(
        gs[0], gs[ng > 1 ? 1 : 0], gs[ng > 2 ? 2 : 0], 8, 3, 4);
  }

  // h2(19) ended in A2[0][:, 512:]
  fc_kernel<<<160, 256, 0, stream>>>(A2[0] + 512, 1024, W_fc, b_fc, out);
}